// Round 16
// baseline (9832.677 us; speedup 1.0000x reference)
//
#include <hip/hip_runtime.h>
#include <cstdint>
#include <cstddef>

constexpr int T_STEPS = 200;
constexpr int BATCH   = 2048;
constexpr int E_DIM   = 256;
constexpr int H_DIM   = 512;
constexpr int P0_DIM  = 256;
constexpr int P1_DIM  = 128;
constexpr float ALPHA = 0.3f;

typedef __attribute__((ext_vector_type(8))) _Float16 f16x8;
typedef __attribute__((ext_vector_type(4))) float f32x4;

__device__ __forceinline__ float sigmoidf_(float x){ return 1.0f/(1.0f+expf(-x)); }

__device__ __forceinline__ unsigned short f2h(float f){
    union { _Float16 h; unsigned short u; } v;
    v.h = (_Float16)f;                 // v_cvt_f16_f32, RNE
    return v.u;
}

#define GLOAD16(gp, lp) __builtin_amdgcn_global_load_lds( \
    (const __attribute__((address_space(1))) unsigned int*)(gp), \
    (__attribute__((address_space(3))) unsigned int*)(lp), 16, 0, 0)

// Stage a [ROWS][64] 16-bit tile into linear LDS, slot-swizzled at the SOURCE
// (m173 pattern): LDS[r][s] holds global k-slot (s ^ (r&7)) of row r.
template<int ROWS>
__device__ __forceinline__ void stage64(const unsigned short* __restrict__ src, int ldk,
                                        char* ldsbase){
    constexpr int TOT = ROWS * 8;          // 16B slots
    const int tid = threadIdx.x;
#pragma unroll
    for (int i = 0; i < TOT/256; ++i){
        const int gsl = i*256 + tid;
        const int r = gsl >> 3, s = gsl & 7;
        const int ksrc = ((s ^ (r & 7)) << 3);
        GLOAD16(src + (size_t)r*ldk + ksrc, ldsbase + gsl*16);
    }
}

// Swizzled b128 fragment read: row-stride 128B (BK=64), kslot in [0,8).
__device__ __forceinline__ f16x8 ldsfragh(const char* ldsbase, int row, int kslot){
    return *(const f16x8*)(ldsbase + row*128 + ((kslot ^ (row & 7)) << 4));
}

// ---------------------------------------------------------------------------
// Fused stream kernel: 512 blocks = 32 brow-groups x 16 h-groups.
// ONE continuous 20-slab pipeline (no phase-boundary drains):
//   slabs 0..3  : gates X part   (A=X, B1=Wg)           -> accg
//   slabs 4..11 : gates H part + extraH (A=AH, B1, B2)  -> accg, acceH
//   slabs 12..19: extraV          (A=AV, B2)            -> acceV
// Per-buf layout: A at +0 (8KB), B1 at +8192 (16KB), B2 at +24576 (4KB);
// bufs at 0 / 32768. Counted vmcnt = next slab's loads/thread (7/6/3, 0 last).
// K-accumulation order per accumulator identical to the r10-verified kernel.
// mode 0 (click): a1=extraH(Hc@Ws0), a2=extraV(Hv@Ws1); writes sc, Hc_new.
// mode 1 (conv):  a1=extraV(Hv@Ws2), a2=extraH(Hc@Ws3); writes sv, hv32, Hv_new.
// WT2 layout: [2048][768], n' = (h/32)*128 + z*32 + (h%32).
// ---------------------------------------------------------------------------
__global__ __launch_bounds__(256, 2) void k_fused(
    const unsigned short* __restrict__ Xh,
    const unsigned short* __restrict__ AH,   // Hc_old (mode 0) / Hc_new (mode 1)
    const unsigned short* __restrict__ AV,   // Hv_old
    const unsigned short* __restrict__ WT2,
    const float* __restrict__ bias,          // [4][512] z-major
    const unsigned short* __restrict__ WsH,  // Ws0 (mode 0) / Ws3 (mode 1)
    const unsigned short* __restrict__ WsV,  // Ws1 (mode 0) / Ws2 (mode 1)
    const float* __restrict__ g,
    float* __restrict__ sstate, float* __restrict__ Hv32,
    unsigned short* __restrict__ Hnew,
    const int mode)
{
    __shared__ __align__(16) char lds[65536];
    const int tid = threadIdx.x;
    const int lane = tid & 63, wid = tid >> 6;
    const int wr = wid >> 1, wc = wid & 1;
    const int lr = lane & 15, lq = lane >> 4;

    // XCD-bijective swizzle: XCD k gets hgrps {2k,2k+1} with all 32 brow-groups.
    const int id = blockIdx.x;
    const int virt = ((id & 7) << 6) | (id >> 3);
    const int hgrp = virt >> 5;      // 0..15
    const int brow = (virt & 31) * 64;
    const int h0   = hgrp * 32;

    f32x4 accg[2][4], acceH[2], acceV[2];
#pragma unroll
    for (int m = 0; m < 2; ++m){
        f32x4 z = {0.f,0.f,0.f,0.f};
#pragma unroll
        for (int n = 0; n < 4; ++n) accg[m][n] = z;
        acceH[m] = z; acceV[m] = z;
    }

    const unsigned short* WTp  = WT2 + (size_t)hgrp*128*768;
    const unsigned short* Ax   = Xh  + (size_t)brow*E_DIM;
    const unsigned short* Ah   = AH  + (size_t)brow*H_DIM;
    const unsigned short* Av   = AV  + (size_t)brow*H_DIM;
    const unsigned short* WsHp = WsH + (size_t)h0*H_DIM;
    const unsigned short* WsVp = WsV + (size_t)h0*H_DIM;

    auto stage_slab = [&](int s, char* buf){
        if (s < 4){
            stage64<64>(Ax + s*64, E_DIM, buf);
            stage64<128>(WTp + s*64, 768, buf + 8192);
        } else if (s < 12){
            const int k = (s - 4)*64;
            stage64<64>(Ah + k, H_DIM, buf);
            stage64<128>(WTp + E_DIM + k, 768, buf + 8192);
            stage64<32>(WsHp + k, 512, buf + 24576);
        } else {
            const int k = (s - 12)*64;
            stage64<64>(Av + k, H_DIM, buf);
            stage64<32>(WsVp + k, 512, buf + 24576);
        }
    };

    stage_slab(0, lds);
    int cur = 0;
#pragma unroll
    for (int s = 0; s < 20; ++s){
        char* bufc = lds + cur*32768;
        if (s + 1 < 20) stage_slab(s + 1, lds + (cur^1)*32768);
        // counted wait: outstanding allowed = next slab's loads/thread
        const int nx = (s + 1 < 20) ? ((s + 1 < 4) ? 6 : ((s + 1 < 12) ? 7 : 3)) : 0;
        if (nx == 7)      asm volatile("s_waitcnt vmcnt(7)" ::: "memory");
        else if (nx == 6) asm volatile("s_waitcnt vmcnt(6)" ::: "memory");
        else if (nx == 3) asm volatile("s_waitcnt vmcnt(3)" ::: "memory");
        else              asm volatile("s_waitcnt vmcnt(0)" ::: "memory");
        __builtin_amdgcn_s_barrier();
        __builtin_amdgcn_sched_barrier(0);
        __builtin_amdgcn_s_setprio(1);
#pragma unroll
        for (int kk = 0; kk < 2; ++kk){
            f16x8 a[2];
#pragma unroll
            for (int m = 0; m < 2; ++m) a[m] = ldsfragh(bufc, wr*32 + m*16 + lr, kk*4 + lq);
            if (s < 12){
#pragma unroll
                for (int n = 0; n < 4; ++n){
                    f16x8 b = ldsfragh(bufc + 8192, wc*64 + n*16 + lr, kk*4 + lq);
#pragma unroll
                    for (int m = 0; m < 2; ++m)
                        accg[m][n] = __builtin_amdgcn_mfma_f32_16x16x32_f16(a[m], b, accg[m][n], 0,0,0);
                }
            }
            if (s >= 4 && s < 12){
                f16x8 b = ldsfragh(bufc + 24576, wc*16 + lr, kk*4 + lq);
#pragma unroll
                for (int m = 0; m < 2; ++m)
                    acceH[m] = __builtin_amdgcn_mfma_f32_16x16x32_f16(a[m], b, acceH[m], 0,0,0);
            }
            if (s >= 12){
                f16x8 b = ldsfragh(bufc + 24576, wc*16 + lr, kk*4 + lq);
#pragma unroll
                for (int m = 0; m < 2; ++m)
                    acceV[m] = __builtin_amdgcn_mfma_f32_16x16x32_f16(a[m], b, acceV[m], 0,0,0);
            }
        }
        __builtin_amdgcn_s_setprio(0);
        __builtin_amdgcn_sched_barrier(0);
        __builtin_amdgcn_s_barrier();
        cur ^= 1;
    }

    // ---- epilogue: gates (activated) + extras (raw) -> LDS (padded) ----
    float* ldsG  = (float*)lds;               // [64][132] fp32 (pad +4)
    float* ldsEH = (float*)(lds + 33792);     // [64][33]
    float* ldsEV = (float*)(lds + 42240);     // [64][33]
#pragma unroll
    for (int m = 0; m < 2; ++m){
#pragma unroll
        for (int n = 0; n < 4; ++n){
            const int col = wc*64 + n*16 + lr;          // 0..127 = z*32 + hl
            const int z = col >> 5, hl = col & 31;
            const float bs = bias[z*H_DIM + h0 + hl];
#pragma unroll
            for (int r = 0; r < 4; ++r){
                const int row = wr*32 + m*16 + lq*4 + r;
                float v = accg[m][n][r] + bs;
                v = (z < 3) ? sigmoidf_(v) : tanhf(v);
                ldsG[row*132 + col] = v;
            }
        }
    }
#pragma unroll
    for (int m = 0; m < 2; ++m){
        const int col = wc*16 + lr;                     // 0..31
#pragma unroll
        for (int r = 0; r < 4; ++r){
            const int row = wr*32 + m*16 + lq*4 + r;
            ldsEH[row*33 + col] = acceH[m][r];
            ldsEV[row*33 + col] = acceV[m][r];
        }
    }
    __syncthreads();

    // ---- inline cell: 256 threads x 8 elems ----
    const int crow = tid >> 2, ch = (tid & 3) * 8;
    const int grow = brow + crow;
    const float gv = g[grow];
    const size_t gbase = (size_t)grow*H_DIM + h0 + ch;
    union U4 { float4 v; float s[4]; };
    U4 sv0, sv1, hv0, hv1;
    sv0.v = *(const float4*)&sstate[gbase];
    sv1.v = *(const float4*)&sstate[gbase + 4];
    if (mode == 1){
        hv0.v = *(const float4*)&Hv32[gbase];
        hv1.v = *(const float4*)&Hv32[gbase + 4];
    }
    U4 sn0, sn1, hn0, hn1;
    union { unsigned short u[8]; f16x8 v; } hh;
#pragma unroll
    for (int e = 0; e < 8; ++e){
        const int hc = ch + e;
        const float f_ = ldsG[crow*132 + hc];
        const float i_ = ldsG[crow*132 + 32 + hc];
        const float o_ = ldsG[crow*132 + 64 + hc];
        const float q_ = ldsG[crow*132 + 96 + hc];
        const float eh = ldsEH[crow*33 + hc];
        const float ev = ldsEV[crow*33 + hc];
        const float a1 = (mode == 0) ? eh : ev;
        const float a2 = (mode == 0) ? ev : eh;
        const float svo = (e < 4) ? sv0.s[e] : sv1.s[e-4];
        float s, hval;
        if (mode == 0){
            const float shat = tanhf((1.0f - gv)*a1 + gv*a2);
            s = shat + i_*q_ + (1.0f - gv)*(f_*svo);
            hval = o_ * tanhf(s);
        } else {
            const float shat = tanhf(a1 + gv*a2);
            s = shat + (1.0f - gv)*svo + gv*(f_*svo + i_*q_);
            const float hvo = (e < 4) ? hv0.s[e] : hv1.s[e-4];
            hval = (1.0f - gv)*hvo + gv*(o_*tanhf(s));
            if (e < 4) hn0.s[e] = hval; else hn1.s[e-4] = hval;
        }
        if (e < 4) sn0.s[e] = s; else sn1.s[e-4] = s;
        hh.u[e] = f2h(hval);
    }
    *(float4*)&sstate[gbase]     = sn0.v;
    *(float4*)&sstate[gbase + 4] = sn1.v;
    if (mode == 1){
        *(float4*)&Hv32[gbase]     = hn0.v;
        *(float4*)&Hv32[gbase + 4] = hn1.v;
    }
    *(f16x8*)&Hnew[gbase] = hh.v;
}

// ---------------------------------------------------------------------------
// Predict (32 rows per pblk), double-buffered staging (counted vmcnt).
// p0=leaky(H@W0+b0), p1=leaky(p0@W1+b1), val=sigmoid(dot(p1,Wf)+bf) (*gmul).
// LDS: buf b at lds + b*36864 (A 4KB @+0, B 32KB @+4096); ldsP at 73728;
// sums at 90112. ~90.6KB (predict kernels run at 1 block/CU).
// r15-verified.
// ---------------------------------------------------------------------------
__device__ __forceinline__ void predict_dev(
    int pblk, const unsigned short* __restrict__ Hh,
    const unsigned short* __restrict__ W0T, const float* __restrict__ b0,
    const unsigned short* __restrict__ W1T, const float* __restrict__ b1,
    const float* __restrict__ Wf, const float* __restrict__ bf_,
    float* gstate, const float* __restrict__ gmul, float* pred, char* lds)
{
    char*  ldsP = lds + 73728;            // [32][512B] p0 fp16 (swizzled)
    float* sums = (float*)(lds + 90112);  // [4][32]
    const int tid = threadIdx.x, lane = tid & 63, w = tid >> 6;
    const int lr = lane & 15, lq = lane >> 4;
    const int brow = pblk * 32;

    f32x4 acc0[2][4];
#pragma unroll
    for (int m = 0; m < 2; ++m)
#pragma unroll
        for (int n = 0; n < 4; ++n){ f32x4 z = {0.f,0.f,0.f,0.f}; acc0[m][n] = z; }

    // ---- p0: K=512, 8 slabs, double-buffered (9 loads/thread/slab) ----
    stage64<32>(Hh + (size_t)brow*H_DIM, H_DIM, lds);
    stage64<256>(W0T, H_DIM, lds + 4096);
    int cur = 0;
    for (int s = 0; s < 8; ++s){
        char* bufc = lds + cur*36864;
        if (s + 1 < 8){
            char* bufn = lds + (cur^1)*36864;
            stage64<32>(Hh + (size_t)brow*H_DIM + (s+1)*64, H_DIM, bufn);
            stage64<256>(W0T + (s+1)*64, H_DIM, bufn + 4096);
            asm volatile("s_waitcnt vmcnt(9)" ::: "memory");
        } else {
            asm volatile("s_waitcnt vmcnt(0)" ::: "memory");
        }
        __builtin_amdgcn_s_barrier();
        __builtin_amdgcn_sched_barrier(0);
#pragma unroll
        for (int kk = 0; kk < 2; ++kk){
            f16x8 a[2], b[4];
#pragma unroll
            for (int m = 0; m < 2; ++m) a[m] = ldsfragh(bufc, m*16 + lr, kk*4 + lq);
#pragma unroll
            for (int n = 0; n < 4; ++n) b[n] = ldsfragh(bufc + 4096, w*64 + n*16 + lr, kk*4 + lq);
#pragma unroll
            for (int m = 0; m < 2; ++m)
#pragma unroll
                for (int n = 0; n < 4; ++n)
                    acc0[m][n] = __builtin_amdgcn_mfma_f32_16x16x32_f16(a[m], b[n], acc0[m][n], 0,0,0);
        }
        __builtin_amdgcn_sched_barrier(0);
        __builtin_amdgcn_s_barrier();
        cur ^= 1;
    }

    // ---- p0 epilogue -> ldsP (swizzled) ----
#pragma unroll
    for (int m = 0; m < 2; ++m){
#pragma unroll
        for (int n = 0; n < 4; ++n){
            const int col = w*64 + n*16 + lr;
            const float bs = b0[col];
#pragma unroll
            for (int r = 0; r < 4; ++r){
                const int row = m*16 + lq*4 + r;
                float x = acc0[m][n][r] + bs;
                x = (x > 0.0f) ? x : ALPHA*x;
                *(unsigned short*)(ldsP + row*512 + ((((col >> 3)) ^ (row & 7)) << 4) + (col & 7)*2) = f2h(x);
            }
        }
    }
    __syncthreads();

    // ---- p1: K=256, 4 slabs, double-buffered B ----
    f32x4 accp[2][2];
#pragma unroll
    for (int m = 0; m < 2; ++m)
#pragma unroll
        for (int n = 0; n < 2; ++n){ f32x4 z = {0.f,0.f,0.f,0.f}; accp[m][n] = z; }

    stage64<128>(W1T, P0_DIM, lds + 4096);
    cur = 0;
    for (int s = 0; s < 4; ++s){
        char* bufc = lds + cur*36864;
        if (s + 1 < 4){
            char* bufn = lds + (cur^1)*36864;
            stage64<128>(W1T + (s+1)*64, P0_DIM, bufn + 4096);
            asm volatile("s_waitcnt vmcnt(4)" ::: "memory");
        } else {
            asm volatile("s_waitcnt vmcnt(0)" ::: "memory");
        }
        __builtin_amdgcn_s_barrier();
        __builtin_amdgcn_sched_barrier(0);
#pragma unroll
        for (int kk = 0; kk < 2; ++kk){
            f16x8 a[2], b[2];
#pragma unroll
            for (int m = 0; m < 2; ++m){
                const int row = m*16 + lr;
                const int slot = s*8 + kk*4 + lq;
                a[m] = *(const f16x8*)(ldsP + row*512 + ((slot ^ (row & 7)) << 4));
            }
#pragma unroll
            for (int n = 0; n < 2; ++n) b[n] = ldsfragh(bufc + 4096, w*32 + n*16 + lr, kk*4 + lq);
#pragma unroll
            for (int m = 0; m < 2; ++m)
#pragma unroll
                for (int n = 0; n < 2; ++n)
                    accp[m][n] = __builtin_amdgcn_mfma_f32_16x16x32_f16(a[m], b[n], accp[m][n], 0,0,0);
        }
        __builtin_amdgcn_sched_barrier(0);
        __builtin_amdgcn_s_barrier();
        cur ^= 1;
    }

    // ---- head ----
    float part[8];
#pragma unroll
    for (int j = 0; j < 8; ++j) part[j] = 0.0f;
#pragma unroll
    for (int m = 0; m < 2; ++m){
#pragma unroll
        for (int n = 0; n < 2; ++n){
            const int col = w*32 + n*16 + lr;
            const float bs = b1[col], wf = Wf[col];
#pragma unroll
            for (int r = 0; r < 4; ++r){
                float x = accp[m][n][r] + bs;
                x = (x > 0.0f) ? x : ALPHA*x;
                part[m*4 + r] += x * wf;
            }
        }
    }
#pragma unroll
    for (int mask = 1; mask < 16; mask <<= 1)
#pragma unroll
        for (int j = 0; j < 8; ++j) part[j] += __shfl_xor(part[j], mask);
    if (lr == 0){
#pragma unroll
        for (int j = 0; j < 8; ++j){
            const int row = (j >> 2)*16 + lq*4 + (j & 3);
            sums[w*32 + row] = part[j];
        }
    }
    __syncthreads();
    if (tid < 32){
        float tot = sums[tid] + sums[32 + tid] + sums[64 + tid] + sums[96 + tid] + bf_[0];
        float val = sigmoidf_(tot);
        const int rowg = brow + tid;
        if (gmul)   val *= gmul[rowg];
        if (gstate) gstate[rowg] = val;
        if (pred)   pred[rowg]   = val;
    }
}

// x-step fp16 convert: 128 blocks x 256 thr x 4 float4.
__device__ __forceinline__ void xcvt_dev(int blk, const float* __restrict__ x,
                                         unsigned short* __restrict__ oh)
{
    const int tid = threadIdx.x;
#pragma unroll
    for (int j = 0; j < 4; ++j){
        const int t = blk*256 + tid + j*32768;
        float4 v = ((const float4*)x)[t];
        ushort4 h;
        h.x = f2h(v.x); h.y = f2h(v.y); h.z = f2h(v.z); h.w = f2h(v.w);
        ((ushort4*)oh)[t] = h;
    }
}

// ---------------------------------------------------------------------------
// LB: [0,64) predict_c (writes gnew, pred_c) | [64,128) predict_v(t-1) reads gold
//     | [128,256) xcvt(t+1)
// ---------------------------------------------------------------------------
__global__ __launch_bounds__(256) void k_LB(
    const unsigned short* __restrict__ Hcn,
    const unsigned short* __restrict__ Wp0Tc, const float* __restrict__ bpc0,
    const unsigned short* __restrict__ Wp1Tc, const float* __restrict__ bpc1,
    const float* __restrict__ Wfcc, const float* __restrict__ bfcc,
    float* __restrict__ gnew, float* __restrict__ predc,
    const unsigned short* __restrict__ Hvb,
    const unsigned short* __restrict__ Wp0Tv, const float* __restrict__ bpv0,
    const unsigned short* __restrict__ Wp1Tv, const float* __restrict__ bpv1,
    const float* __restrict__ Wfcv, const float* __restrict__ bfcv,
    const float* __restrict__ gold, float* __restrict__ predv,
    const float* __restrict__ xnext, unsigned short* __restrict__ Xnh)
{
    __shared__ __align__(16) char lds[90624];
    const int id = blockIdx.x;
    if (id < 64){
        predict_dev(id, Hcn, Wp0Tc, bpc0, Wp1Tc, bpc1, Wfcc, bfcc,
                    gnew, nullptr, predc, lds);
    } else if (id < 128){
        if (predv) predict_dev(id - 64, Hvb, Wp0Tv, bpv0, Wp1Tv, bpv1, Wfcv, bfcv,
                               nullptr, gold, predv, lds);
    } else {
        if (Xnh) xcvt_dev(id - 128, xnext, Xnh);
    }
}

// ---------------------------------------------------------------------------
// Standalone predict (init g0 / final pred_v) and x0 convert.
// ---------------------------------------------------------------------------
__global__ __launch_bounds__(256) void k_predict_g(
    const unsigned short* __restrict__ Hh,
    const unsigned short* __restrict__ W0T, const float* __restrict__ b0,
    const unsigned short* __restrict__ W1T, const float* __restrict__ b1,
    const float* __restrict__ Wf, const float* __restrict__ bf_,
    float* gstate, const float* __restrict__ gmul, float* pred)
{
    __shared__ __align__(16) char lds[90624];
    predict_dev(blockIdx.x, Hh, W0T, b0, W1T, b1, Wf, bf_, gstate, gmul, pred, lds);
}

__global__ __launch_bounds__(256) void k_xcvt_g(const float* __restrict__ x,
                                                unsigned short* __restrict__ oh)
{
    xcvt_dev(blockIdx.x, x, oh);
}

// ---------------------------------------------------------------------------
// Prep kernels. WT2 layout: n' = (h/32)*128 + z*32 + (h%32), k in [0,768).
// ---------------------------------------------------------------------------
__global__ __launch_bounds__(256) void k_wcat(const float* __restrict__ Wx,
                                              const float* __restrict__ Wh,
                                              unsigned short* __restrict__ oh){
    const int n = blockIdx.y;                 // n' in [0,2048)
    const int k = blockIdx.x*256 + threadIdx.x;
    const int z = (n >> 5) & 3;
    const int h = ((n >> 7) << 5) | (n & 31);
    float v = (k < 256) ? Wx[((size_t)z*E_DIM + k)*H_DIM + h]
                        : Wh[((size_t)z*H_DIM + (k - 256))*H_DIM + h];
    oh[(size_t)n*768 + k] = f2h(v);
}

__global__ __launch_bounds__(256) void k_trans(const float* __restrict__ in,
                                               unsigned short* __restrict__ oh,
                                               int K, int N){
    const int k = blockIdx.x*256 + threadIdx.x;
    const int n = blockIdx.y;
    if (k < K) oh[(size_t)n*K + k] = f2h(in[(size_t)k*N + n]);
}

__global__ __launch_bounds__(256) void k_init(float* __restrict__ sc, float* __restrict__ sv,
                                              float* __restrict__ hv32,
                                              unsigned short* __restrict__ hc0,
                                              unsigned short* __restrict__ hv0){
    const int i = blockIdx.x*256 + threadIdx.x;
    sc[i] = 0.0f; sv[i] = 0.0f; hv32[i] = 0.0f;
    hc0[i] = 0; hv0[i] = 0;
}

// ---------------------------------------------------------------------------
extern "C" void kernel_launch(void* const* d_in, const int* in_sizes, int n_in,
                              void* d_out, int out_size, void* d_ws, size_t ws_size,
                              hipStream_t stream)
{
    (void)in_sizes; (void)n_in; (void)out_size; (void)ws_size;

    const float* inputs = (const float*)d_in[0];
    const float* Wx_c   = (const float*)d_in[1];
    const float* bx_c   = (const float*)d_in[2];
    const float* Wh_c   = (const float*)d_in[3];
    const float* Wx_v   = (const float*)d_in[4];
    const float* bx_v   = (const float*)d_in[5];
    const float* Wh_v   = (const float*)d_in[6];
    const float* Ws     = (const float*)d_in[7];
    const float* Wpc0   = (const float*)d_in[8];
    const float* bpc0   = (const float*)d_in[9];
    const float* Wpc1   = (const float*)d_in[10];
    const float* bpc1   = (const float*)d_in[11];
    const float* Wfcc   = (const float*)d_in[12];
    const float* bfcc   = (const float*)d_in[13];
    const float* Wpv0   = (const float*)d_in[14];
    const float* bpv0   = (const float*)d_in[15];
    const float* Wpv1   = (const float*)d_in[16];
    const float* bpv1   = (const float*)d_in[17];
    const float* Wfcv   = (const float*)d_in[18];
    const float* bfcv   = (const float*)d_in[19];
    float* out = (float*)d_out;

    char* ws = (char*)d_ws;
    size_t off = 0;
    auto allocB = [&](size_t bytes) -> char* {
        char* p = ws + off;
        off = (off + bytes + 255) & ~(size_t)255;
        return p;
    };
    const size_t BH = (size_t)BATCH * H_DIM;
    const size_t BE = (size_t)BATCH * E_DIM;

    unsigned short* Xh[2];
    Xh[0] = (unsigned short*)allocB(BE*2);
    Xh[1] = (unsigned short*)allocB(BE*2);
    unsigned short* WT2c  = (unsigned short*)allocB((size_t)2048*768*2);
    unsigned short* WT2v  = (unsigned short*)allocB((size_t)2048*768*2);
    unsigned short* WsT   = (unsigned short*)allocB((size_t)4*H_DIM*H_DIM*2);
    unsigned short* Wp0Tc = (unsigned short*)allocB((size_t)P0_DIM*H_DIM*2);
    unsigned short* Wp0Tv = (unsigned short*)allocB((size_t)P0_DIM*H_DIM*2);
    unsigned short* Wp1Tc = (unsigned short*)allocB((size_t)P1_DIM*P0_DIM*2);
    unsigned short* Wp1Tv = (unsigned short*)allocB((size_t)P1_DIM*P0_DIM*2);
    unsigned short* Hc[2], *Hv[2];
    Hc[0] = (unsigned short*)allocB(BH*2);
    Hc[1] = (unsigned short*)allocB(BH*2);
    Hv[0] = (unsigned short*)allocB(BH*2);
    Hv[1] = (unsigned short*)allocB(BH*2);
    float* sc    = (float*)allocB(BH*4);
    float* sv    = (float*)allocB(BH*4);
    float* hv32  = (float*)allocB(BH*4);
    float* gbuf[2];
    gbuf[0] = (float*)allocB(BATCH*4);
    gbuf[1] = (float*)allocB(BATCH*4);

    const dim3 thr(256);
    const size_t HH = (size_t)H_DIM * H_DIM;

    // ---- one-time weight conversion ----
    k_wcat<<<dim3(3, 2048), thr, 0, stream>>>(Wx_c, Wh_c, WT2c);
    k_wcat<<<dim3(3, 2048), thr, 0, stream>>>(Wx_v, Wh_v, WT2v);
    for (int i = 0; i < 4; ++i)
        k_trans<<<dim3(2, 512), thr, 0, stream>>>(Ws + i*HH, WsT + i*HH, H_DIM, H_DIM);
    k_trans<<<dim3(2, 256), thr, 0, stream>>>(Wpc0, Wp0Tc, H_DIM, P0_DIM);
    k_trans<<<dim3(2, 256), thr, 0, stream>>>(Wpv0, Wp0Tv, H_DIM, P0_DIM);
    k_trans<<<dim3(1, 128), thr, 0, stream>>>(Wpc1, Wp1Tc, P0_DIM, P1_DIM);
    k_trans<<<dim3(1, 128), thr, 0, stream>>>(Wpv1, Wp1Tv, P0_DIM, P1_DIM);

    // ---- init: zero states; g0 = predict_c(zeros) -> gbuf[0]; convert x(0) ----
    k_init<<<4096, thr, 0, stream>>>(sc, sv, hv32, Hc[0], Hv[0]);
    k_predict_g<<<64, thr, 0, stream>>>(Hc[0], Wp0Tc, bpc0, Wp1Tc, bpc1, Wfcc, bfcc,
                                        gbuf[0], nullptr, nullptr);
    k_xcvt_g<<<128, thr, 0, stream>>>(inputs, Xh[0]);

    for (int t = 0; t < T_STEPS; ++t){
        const int cur = t & 1, nxt = cur ^ 1;

        // LA: fused click stream (gates_c + a1 + a2 + cell_c)
        k_fused<<<512, thr, 0, stream>>>(Xh[cur], Hc[cur], Hv[cur],
                                         WT2c, bx_c,
                                         WsT + 0*HH,   // Ws0 -> extraH = a1
                                         WsT + 1*HH,   // Ws1 -> extraV = a2
                                         gbuf[cur], sc, nullptr, Hc[nxt], 0);

        // LB: predict_c (g_new) + predict_v(t-1) (g_old) + xcvt(t+1)
        k_LB<<<256, thr, 0, stream>>>(Hc[nxt], Wp0Tc, bpc0, Wp1Tc, bpc1, Wfcc, bfcc,
                                      gbuf[nxt], out + (size_t)t*BATCH,
                                      Hv[cur], Wp0Tv, bpv0, Wp1Tv, bpv1, Wfcv, bfcv,
                                      gbuf[cur],
                                      (t > 0) ? out + (size_t)(T_STEPS + t - 1)*BATCH
                                              : nullptr,
                                      inputs + (size_t)(t+1)*BE,
                                      (t + 1 < T_STEPS) ? Xh[nxt] : nullptr);

        // LC: fused conversion stream (gates_v + a2v + a1v + cell_v)
        k_fused<<<512, thr, 0, stream>>>(Xh[cur], Hc[nxt], Hv[cur],
                                         WT2v, bx_v,
                                         WsT + 3*HH,   // Ws3 -> extraH = a2v
                                         WsT + 2*HH,   // Ws2 -> extraV = a1v
                                         gbuf[nxt], sv, hv32, Hv[nxt], 1);
    }
    // tail: pred_v(T-1); Hv_new(199)=Hv[0], g_new(199)=gbuf[0]
    k_predict_g<<<64, thr, 0, stream>>>(Hv[0], Wp0Tv, bpv0, Wp1Tv, bpv1, Wfcv, bfcv,
                                        nullptr, gbuf[0],
                                        out + (size_t)(2*T_STEPS - 1)*BATCH);
}